// Round 10
// baseline (1284.273 us; speedup 1.0000x reference)
//
#include <hip/hip_runtime.h>
#include <hip/hip_cooperative_groups.h>
#include <math.h>

namespace cg = cooperative_groups;

#define B_   32
#define N_   128
#define H_   100
#define ROWS (B_ * N_)    // 4096
#define RH   (ROWS * H_)  // 409600
#define OUTSZ (B_ * H_)   // 3200
#define RPB  8            // rows per block in k_all

// ===========================================================================
// r10 COOPERATIVE FUSED KERNEL (fixed r9): grid 512 x 1024 threads, 8 rows
// per block = only 2 blocks/CU needed co-resident (big capacity margin vs
// r9's zero-margin 2048x256 which failed to launch -> all-zero output).
// Geometry = r3's (proven perf-identical to r0: 51us/pass). Structure:
//  - edges staged + ballot'd ONCE (was 3x); nodes staged once; hidden lives
//    in LDS; hv lives in a register; initial hw projection folded in.
//  - only hw crosses global per pass (hwA/hwB), ordered by fence+grid.sync.
//  - launch return code CHECKED; fallback = proven r0 4-dispatch path.
// ===========================================================================
__global__ __launch_bounds__(1024, 8) void k_all(const float* __restrict__ nodes,
                                                 const float* __restrict__ edges,
                                                 const float* __restrict__ Wv,
                                                 const float* __restrict__ Ww,
                                                 const float* __restrict__ We,
                                                 const float* __restrict__ Wu,
                                                 const float* __restrict__ Wr,
                                                 float* __restrict__ hwA,
                                                 float* __restrict__ hwB,
                                                 float* __restrict__ out) {
    cg::grid_group grid = cg::this_grid();

    __shared__ float4 e_s[RPB][N_];        // 16 KB, persists all passes
    __shared__ float  asum_s[RPB][2];
    __shared__ unsigned qmask_s[RPB][4];
    __shared__ float  hid_s[RPB][H_];      // current hidden (own 8 rows)
    __shared__ float  msg_s[RPB][H_];
    __shared__ float  nod_s[RPB][H_];      // original nodes (readout)
    __shared__ float  red_s[RPB][H_];

    // batch-affine swizzle: co-resident blocks (≡ mod 256) share batch b
    const int bx = blockIdx.x;             // grid = 512
    const int cu = bx & 255, slot = bx >> 8;    // slot 0..1
    const int b = cu >> 3;
    const int vt = (cu & 7) + slot * 8;    // 0..15 (16 tiles x 8 rows)
    const int row0 = b * N_ + vt * RPB;

    const int t = threadIdx.x;
    const int rg = t >> 7, j = t & 127;    // row-group 0..7, column lane
    const int wv = t >> 6, lane = t & 63;  // wave 0..15
    const int row = row0 + rg;
    const bool act = (j < H_);

    {   // zero out[] (atomicAdds happen only after 3 grid syncs)
        const int gid = bx * 1024 + t;
        if (gid < OUTSZ) out[gid] = 0.f;
    }
    {   // stage 8 rows' edges ONCE; ballot masks; half-row sums
        const float4* eg = (const float4*)(edges + (size_t)row0 * N_ * 4);
        const float4 e = eg[t];            // t == rg*128 + w, coalesced
        e_s[rg][j] = e;
        float s = (e.x + e.y) + (e.z + e.w);
        const unsigned long long bal = __ballot(s != 0.f);
        const int rowq = wv >> 1, half = wv & 1;   // wave-uniform
        if (lane == 0) {
            qmask_s[rowq][half * 2]     = (unsigned)bal;
            qmask_s[rowq][half * 2 + 1] = (unsigned)(bal >> 32);
        }
#pragma unroll
        for (int off = 32; off > 0; off >>= 1) s += __shfl_down(s, off);
        if (lane == 0) asum_s[rowq][half] = s;
    }
    {   // stage nodes ONCE (initial hidden + readout operand): 200 float4
        const float4* ng = (const float4*)(nodes + (size_t)row0 * H_);
        if (t < 200) {
            const float4 v = ng[t];
            ((float4*)nod_s)[t] = v;
            ((float4*)hid_s)[t] = v;
        }
    }
    __syncthreads();

    const float nm = ((asum_s[rg][0] + asum_s[rg][1]) != 0.f) ? 1.f : 0.f;

    // ---- folded k_proj0: hv (register) + hw -> hwA, from initial hidden ----
    float hvv = 0.f;
    if (act) {
        const float4* h4p = (const float4*)hid_s[rg];
        float va = 0.f, wa = 0.f;
#pragma unroll 5
        for (int k4 = 0; k4 < 25; ++k4) {
            const float4 h4 = h4p[k4];
            const int k = k4 * 4;
            va = fmaf(h4.x, Wv[(k + 0) * H_ + j], va);
            wa = fmaf(h4.x, Ww[(k + 0) * H_ + j], wa);
            va = fmaf(h4.y, Wv[(k + 1) * H_ + j], va);
            wa = fmaf(h4.y, Ww[(k + 1) * H_ + j], wa);
            va = fmaf(h4.z, Wv[(k + 2) * H_ + j], va);
            wa = fmaf(h4.z, Ww[(k + 2) * H_ + j], wa);
            va = fmaf(h4.w, Wv[(k + 3) * H_ + j], va);
            wa = fmaf(h4.w, Ww[(k + 3) * H_ + j], wa);
        }
        hvv = va;
        hwA[(size_t)row * H_ + j] = wa;
    }
    __threadfence();
    grid.sync();
    __threadfence();

    for (int pass = 0; pass < 3; ++pass) {
        const float* hin = (pass & 1) ? hwB : hwA;
        float* hout      = (pass & 1) ? hwA : hwB;

        // ---- message loop (byte-identical inner code to r0) ----
        if (act) {
            const float we0 = We[0 * H_ + j], we1 = We[1 * H_ + j];
            const float we2 = We[2 * H_ + j], we3 = We[3 * H_ + j];
            const float* hwp = hin + (size_t)b * N_ * H_ + j;
            float acc = 0.f;
            for (int c = 0; c < 4; ++c) {         // 4 chunks of 32 w
                const unsigned mq =
                    __builtin_amdgcn_readfirstlane(qmask_s[rg][c]);
                const float4* ec = &e_s[rg][c * 32];
                const float*  hc = hwp + (size_t)(c * 32) * H_;
#pragma unroll 8
                for (int w8 = 0; w8 < 32; ++w8) {
                    const float4 e = ec[w8];          // LDS b128 broadcast
                    const float  hww = hc[w8 * H_];   // coalesced global
                    const float  m = ((mq >> w8) & 1u) ? 1.f : 0.f;
                    float p = hvv + hww;
                    p = fmaf(e.x, we0, p);
                    p = fmaf(e.y, we1, p);
                    p = fmaf(e.z, we2, p);
                    p = fmaf(e.w, we3, p);
                    acc = fmaf(m, fmaxf(p, 0.f), acc);
                }
            }
            msg_s[rg][j] = acc;
        }
        __syncthreads();

        // ---- update GEMM: u = [hid|msg] @ Wu ----
        float nh = 0.f;
        if (act) {
            const float4* h4p = (const float4*)hid_s[rg];
            const float4* m4p = (const float4*)msg_s[rg];
            float u = 0.f;
#pragma unroll 5
            for (int k4 = 0; k4 < 25; ++k4) {
                const float4 h4 = h4p[k4];
                const int k = k4 * 4;
                u = fmaf(h4.x, Wu[(k + 0) * H_ + j], u);
                u = fmaf(h4.y, Wu[(k + 1) * H_ + j], u);
                u = fmaf(h4.z, Wu[(k + 2) * H_ + j], u);
                u = fmaf(h4.w, Wu[(k + 3) * H_ + j], u);
            }
#pragma unroll 5
            for (int k4 = 0; k4 < 25; ++k4) {
                const float4 m4 = m4p[k4];
                const int k = H_ + k4 * 4;
                u = fmaf(m4.x, Wu[(k + 0) * H_ + j], u);
                u = fmaf(m4.y, Wu[(k + 1) * H_ + j], u);
                u = fmaf(m4.z, Wu[(k + 2) * H_ + j], u);
                u = fmaf(m4.w, Wu[(k + 3) * H_ + j], u);
            }
            nh = (nm != 0.f) ? tanhf(u) : hid_s[rg][j];
        }
        __syncthreads();               // all reads of old hid_s complete
        if (act) hid_s[rg][j] = nh;    // commit new hidden
        __syncthreads();               // new hid_s visible block-wide

        if (pass < 2) {
            // ---- next pass's hv (register) / hw (global) from new hidden ----
            if (act) {
                const float4* h4p = (const float4*)hid_s[rg];
                float va = 0.f, wa = 0.f;
#pragma unroll 5
                for (int k4 = 0; k4 < 25; ++k4) {
                    const float4 h4 = h4p[k4];
                    const int k = k4 * 4;
                    va = fmaf(h4.x, Wv[(k + 0) * H_ + j], va);
                    wa = fmaf(h4.x, Ww[(k + 0) * H_ + j], wa);
                    va = fmaf(h4.y, Wv[(k + 1) * H_ + j], va);
                    wa = fmaf(h4.y, Ww[(k + 1) * H_ + j], wa);
                    va = fmaf(h4.z, Wv[(k + 2) * H_ + j], va);
                    wa = fmaf(h4.z, Ww[(k + 2) * H_ + j], wa);
                    va = fmaf(h4.w, Wv[(k + 3) * H_ + j], va);
                    wa = fmaf(h4.w, Ww[(k + 3) * H_ + j], wa);
                }
                hvv = va;
                hout[(size_t)row * H_ + j] = wa;
            }
            __threadfence();
            grid.sync();               // publish hw to all blocks of batch b
            __threadfence();
        } else {
            // ---- readout: relu([hid_new | nodes] @ Wr) * nm, sum-pooled ----
            if (act) {
                const float4* h4p = (const float4*)hid_s[rg];
                const float4* n4p = (const float4*)nod_s[rg];
                float u = 0.f;
#pragma unroll 5
                for (int k4 = 0; k4 < 25; ++k4) {
                    const float4 h4 = h4p[k4];
                    const int k = k4 * 4;
                    u = fmaf(h4.x, Wr[(k + 0) * H_ + j], u);
                    u = fmaf(h4.y, Wr[(k + 1) * H_ + j], u);
                    u = fmaf(h4.z, Wr[(k + 2) * H_ + j], u);
                    u = fmaf(h4.w, Wr[(k + 3) * H_ + j], u);
                }
#pragma unroll 5
                for (int k4 = 0; k4 < 25; ++k4) {
                    const float4 n4 = n4p[k4];
                    const int k = H_ + k4 * 4;
                    u = fmaf(n4.x, Wr[(k + 0) * H_ + j], u);
                    u = fmaf(n4.y, Wr[(k + 1) * H_ + j], u);
                    u = fmaf(n4.z, Wr[(k + 2) * H_ + j], u);
                    u = fmaf(n4.w, Wr[(k + 3) * H_ + j], u);
                }
                red_s[rg][j] = nm * fmaxf(u, 0.f);
            }
            __syncthreads();
            if (t < H_) {
                float ssum = 0.f;
#pragma unroll
                for (int rr = 0; rr < RPB; ++rr) ssum += red_s[rr][t];
                atomicAdd(out + b * H_ + t, ssum);
            }
        }
    }
}

// ===========================================================================
// FALLBACK: the proven r0 4-dispatch path (198.9 us, harness-verified).
// Used when the cooperative launch is rejected (capacity / capture).
// ===========================================================================
__global__ __launch_bounds__(256, 6) void k_proj0(const float* __restrict__ nodes,
                                                  const float* __restrict__ Ww,
                                                  float* __restrict__ hw,
                                                  float* __restrict__ out) {
    __shared__ float nod_s[2][H_];
    const int row0 = blockIdx.x * 2;
    const int t = threadIdx.x, r = t >> 7, j = t & 127;
    {
        const int gid = blockIdx.x * 256 + t;
        if (gid < OUTSZ) out[gid] = 0.f;
    }
    {
        const float4* ng = (const float4*)(nodes + (size_t)row0 * H_);
        if (t < 50) ((float4*)nod_s)[t] = ng[t];
    }
    __syncthreads();
    if (j >= H_) return;
    const float4* h4p = (const float4*)nod_s[r];
    float wa = 0.f;
#pragma unroll 5
    for (int k4 = 0; k4 < 25; ++k4) {
        const float4 h4 = h4p[k4];
        const int k = k4 * 4;
        wa = fmaf(h4.x, Ww[(k + 0) * H_ + j], wa);
        wa = fmaf(h4.y, Ww[(k + 1) * H_ + j], wa);
        wa = fmaf(h4.z, Ww[(k + 2) * H_ + j], wa);
        wa = fmaf(h4.w, Ww[(k + 3) * H_ + j], wa);
    }
    hw[(size_t)(row0 + r) * H_ + j] = wa;
}

template <int MODE, int INIT_HV>
__global__ __launch_bounds__(256, 6) void k_pass(const float* __restrict__ edges,
                                                 const float* __restrict__ We,
                                                 const float* __restrict__ Wu,
                                                 const float* __restrict__ Wv,
                                                 const float* __restrict__ Ww,
                                                 const float* __restrict__ Wr,
                                                 const float* __restrict__ nodes,
                                                 float* __restrict__ hv_io,
                                                 const float* __restrict__ hw_in,
                                                 float* __restrict__ hw_out,
                                                 const float* __restrict__ hid_in,
                                                 float* __restrict__ hidden,
                                                 float* __restrict__ out) {
    __shared__ float4 e_s[2][N_];
    __shared__ float  asum_part[4];
    __shared__ unsigned qmask_s[2][4];
    __shared__ float  hid_s[2][H_];
    __shared__ float  msg_s[2][H_];
    __shared__ float  hn_s[2][H_];
    __shared__ float  nod_s[2][H_];
    __shared__ float  red_s[2][H_];

    const int bx = blockIdx.x;
    const int cu = bx & 255, slot = bx >> 8;
    const int b = cu >> 3;
    const int vt = (cu & 7) + slot * 8;
    const int row0 = b * N_ + vt * 2;

    const int t = threadIdx.x, r = t >> 7, j = t & 127;
    const int wv = t >> 6, lane = t & 63;
    const int row = row0 + r;
    const bool act = (j < H_);

    {
        const float4* eg = (const float4*)(edges + (size_t)row0 * N_ * 4);
        const float4 e = eg[t];
        e_s[r][j] = e;
        float s = (e.x + e.y) + (e.z + e.w);
        const unsigned long long bal = __ballot(s != 0.f);
        if (lane == 0) {
            qmask_s[wv >> 1][(wv & 1) * 2]     = (unsigned)bal;
            qmask_s[wv >> 1][(wv & 1) * 2 + 1] = (unsigned)(bal >> 32);
        }
#pragma unroll
        for (int off = 32; off > 0; off >>= 1) s += __shfl_down(s, off);
        if (lane == 0) asum_part[wv] = s;
    }
    {
        const float4* hg = (const float4*)(hid_in + (size_t)row0 * H_);
        if (t < 50) ((float4*)hid_s)[t] = hg[t];
        if (MODE == 2) {
            const float4* ng = (const float4*)(nodes + (size_t)row0 * H_);
            if (t < 50) ((float4*)nod_s)[t] = ng[t];
        }
    }
    __syncthreads();

    const float nm = ((asum_part[2 * r] + asum_part[2 * r + 1]) != 0.f) ? 1.f : 0.f;

    if (act) {
        float hvv;
        if (INIT_HV) {
            const float4* h4p = (const float4*)hid_s[r];
            float va = 0.f;
#pragma unroll 5
            for (int k4 = 0; k4 < 25; ++k4) {
                const float4 h4 = h4p[k4];
                const int k = k4 * 4;
                va = fmaf(h4.x, Wv[(k + 0) * H_ + j], va);
                va = fmaf(h4.y, Wv[(k + 1) * H_ + j], va);
                va = fmaf(h4.z, Wv[(k + 2) * H_ + j], va);
                va = fmaf(h4.w, Wv[(k + 3) * H_ + j], va);
            }
            hvv = va;
        } else {
            hvv = hv_io[(size_t)row * H_ + j];
        }
        const float we0 = We[0 * H_ + j], we1 = We[1 * H_ + j];
        const float we2 = We[2 * H_ + j], we3 = We[3 * H_ + j];
        const float* hwp = hw_in + (size_t)b * N_ * H_ + j;
        float acc = 0.f;
        for (int c = 0; c < 4; ++c) {
            const unsigned mq =
                __builtin_amdgcn_readfirstlane(qmask_s[r][c]);
            const float4* ec = &e_s[r][c * 32];
            const float*  hc = hwp + (size_t)(c * 32) * H_;
#pragma unroll 8
            for (int w8 = 0; w8 < 32; ++w8) {
                const float4 e = ec[w8];
                const float  hww = hc[w8 * H_];
                const float  m = ((mq >> w8) & 1u) ? 1.f : 0.f;
                float p = hvv + hww;
                p = fmaf(e.x, we0, p);
                p = fmaf(e.y, we1, p);
                p = fmaf(e.z, we2, p);
                p = fmaf(e.w, we3, p);
                acc = fmaf(m, fmaxf(p, 0.f), acc);
            }
        }
        msg_s[r][j] = acc;
    }
    __syncthreads();

    if (act) {
        const float4* h4p = (const float4*)hid_s[r];
        const float4* m4p = (const float4*)msg_s[r];
        float u = 0.f;
#pragma unroll 5
        for (int k4 = 0; k4 < 25; ++k4) {
            const float4 h4 = h4p[k4];
            const int k = k4 * 4;
            u = fmaf(h4.x, Wu[(k + 0) * H_ + j], u);
            u = fmaf(h4.y, Wu[(k + 1) * H_ + j], u);
            u = fmaf(h4.z, Wu[(k + 2) * H_ + j], u);
            u = fmaf(h4.w, Wu[(k + 3) * H_ + j], u);
        }
#pragma unroll 5
        for (int k4 = 0; k4 < 25; ++k4) {
            const float4 m4 = m4p[k4];
            const int k = H_ + k4 * 4;
            u = fmaf(m4.x, Wu[(k + 0) * H_ + j], u);
            u = fmaf(m4.y, Wu[(k + 1) * H_ + j], u);
            u = fmaf(m4.z, Wu[(k + 2) * H_ + j], u);
            u = fmaf(m4.w, Wu[(k + 3) * H_ + j], u);
        }
        const float nh = (nm != 0.f) ? tanhf(u) : hid_s[r][j];
        hn_s[r][j] = nh;
        if (MODE == 1) hidden[(size_t)row * H_ + j] = nh;
    }
    __syncthreads();

    if (MODE == 1) {
        if (act) {
            const float4* h4p = (const float4*)hn_s[r];
            float va = 0.f, wa = 0.f;
#pragma unroll 5
            for (int k4 = 0; k4 < 25; ++k4) {
                const float4 h4 = h4p[k4];
                const int k = k4 * 4;
                va = fmaf(h4.x, Wv[(k + 0) * H_ + j], va);
                wa = fmaf(h4.x, Ww[(k + 0) * H_ + j], wa);
                va = fmaf(h4.y, Wv[(k + 1) * H_ + j], va);
                wa = fmaf(h4.y, Ww[(k + 1) * H_ + j], wa);
                va = fmaf(h4.z, Wv[(k + 2) * H_ + j], va);
                wa = fmaf(h4.z, Ww[(k + 2) * H_ + j], wa);
                va = fmaf(h4.w, Wv[(k + 3) * H_ + j], va);
                wa = fmaf(h4.w, Ww[(k + 3) * H_ + j], wa);
            }
            hv_io[(size_t)row * H_ + j] = va;
            hw_out[(size_t)row * H_ + j] = wa;
        }
    } else {
        if (act) {
            const float4* h4p = (const float4*)hn_s[r];
            const float4* n4p = (const float4*)nod_s[r];
            float u = 0.f;
#pragma unroll 5
            for (int k4 = 0; k4 < 25; ++k4) {
                const float4 h4 = h4p[k4];
                const int k = k4 * 4;
                u = fmaf(h4.x, Wr[(k + 0) * H_ + j], u);
                u = fmaf(h4.y, Wr[(k + 1) * H_ + j], u);
                u = fmaf(h4.z, Wr[(k + 2) * H_ + j], u);
                u = fmaf(h4.w, Wr[(k + 3) * H_ + j], u);
            }
#pragma unroll 5
            for (int k4 = 0; k4 < 25; ++k4) {
                const float4 n4 = n4p[k4];
                const int k = H_ + k4 * 4;
                u = fmaf(n4.x, Wr[(k + 0) * H_ + j], u);
                u = fmaf(n4.y, Wr[(k + 1) * H_ + j], u);
                u = fmaf(n4.z, Wr[(k + 2) * H_ + j], u);
                u = fmaf(n4.w, Wr[(k + 3) * H_ + j], u);
            }
            red_s[r][j] = nm * fmaxf(u, 0.f);
        }
        __syncthreads();
        if (t < H_) atomicAdd(out + b * H_ + t, red_s[0][t] + red_s[1][t]);
    }
}

// ---------------------------------------------------------------------------
extern "C" void kernel_launch(void* const* d_in, const int* in_sizes, int n_in,
                              void* d_out, int out_size, void* d_ws, size_t ws_size,
                              hipStream_t stream) {
    const float* nodes = (const float*)d_in[0];
    const float* edges = (const float*)d_in[1];
    const float* Wv    = (const float*)d_in[2];
    const float* Ww    = (const float*)d_in[3];
    const float* We    = (const float*)d_in[4];
    const float* Wu    = (const float*)d_in[5];
    const float* Wr    = (const float*)d_in[6];
    float* out = (float*)d_out;

    float* hidden = (float*)d_ws;     // RH (fallback only)
    float* hv     = hidden + RH;      // RH (fallback only)
    float* hwA    = hv + RH;          // RH
    float* hwB    = hwA + RH;         // RH

    void* args[] = {(void*)&nodes, (void*)&edges, (void*)&Wv, (void*)&Ww,
                    (void*)&We,    (void*)&Wu,    (void*)&Wr,
                    (void*)&hwA,   (void*)&hwB,   (void*)&out};
    hipError_t err = hipLaunchCooperativeKernel((void*)k_all, dim3(ROWS / RPB),
                                                dim3(1024), args, 0, stream);
    if (err != hipSuccess) {
        (void)hipGetLastError();      // clear sticky error, take proven path
        k_proj0<<<ROWS / 2, 256, 0, stream>>>(nodes, Ww, hwA, out);
        k_pass<1, 1><<<ROWS / 2, 256, 0, stream>>>(edges, We, Wu, Wv, Ww, Wr,
                                                   nodes, hv, hwA, hwB, nodes,
                                                   hidden, out);
        k_pass<1, 0><<<ROWS / 2, 256, 0, stream>>>(edges, We, Wu, Wv, Ww, Wr,
                                                   nodes, hv, hwB, hwA, hidden,
                                                   hidden, out);
        k_pass<2, 0><<<ROWS / 2, 256, 0, stream>>>(edges, We, Wu, Wv, Ww, Wr,
                                                   nodes, hv, hwA, hwB, hidden,
                                                   hidden, out);
    }
}

// Round 11
// 199.310 us; speedup vs baseline: 6.4436x; 6.4436x over previous
//
#include <hip/hip_runtime.h>
#include <math.h>

#define B_   32
#define N_   128
#define H_   100
#define ROWS (B_ * N_)    // 4096
#define RH   (ROWS * H_)  // 409600
#define OUTSZ (B_ * H_)   // 3200

// ---------------------------------------------------------------------------
// K1: hw = nodes@Ww ONLY (initial hv computed in-register by pass 1).
// Also zero-initializes out. (unchanged from the 192us baseline)
__global__ __launch_bounds__(256, 6) void k_proj0(const float* __restrict__ nodes,
                                                  const float* __restrict__ Ww,
                                                  float* __restrict__ hw,
                                                  float* __restrict__ out) {
    __shared__ float nod_s[2][H_];
    const int row0 = blockIdx.x * 2;
    const int t = threadIdx.x, r = t >> 7, j = t & 127;
    {   // zero out[] (dispatches before any atomicAdd; stream-ordered)
        const int gid = blockIdx.x * 256 + t;
        if (gid < OUTSZ) out[gid] = 0.f;
    }
    {
        const float4* ng = (const float4*)(nodes + (size_t)row0 * H_);
        if (t < 50) ((float4*)nod_s)[t] = ng[t];
    }
    __syncthreads();
    if (j >= H_) return;
    const float4* h4p = (const float4*)nod_s[r];
    float wa = 0.f;
#pragma unroll 5
    for (int k4 = 0; k4 < 25; ++k4) {
        const float4 h4 = h4p[k4];
        const int k = k4 * 4;
        wa = fmaf(h4.x, Ww[(k + 0) * H_ + j], wa);
        wa = fmaf(h4.y, Ww[(k + 1) * H_ + j], wa);
        wa = fmaf(h4.z, Ww[(k + 2) * H_ + j], wa);
        wa = fmaf(h4.w, Ww[(k + 3) * H_ + j], wa);
    }
    hw[(size_t)(row0 + r) * H_ + j] = wa;
}

// ===========================================================================
// r11 A-variant: SINGLE-ROW 128-thread blocks, grid 4096 = 16 wg/CU x 2 waves
// = 32 waves/CU potential (vs 8 wg x 4 = measured ~19). Mechanism: fitted
// model over r0/r1/r7 occupancy sweep: t_pass ~ 38us + 270/W (W = waves/CU).
// Raising W 19->~28 predicts ~47us/pass. Inner code byte-identical to r0.
// Used for passes 1 and 3; pass 2 keeps the proven 256-thread kernel ->
// the per-dispatch counters are a within-run A/B of geometry alone.
// ===========================================================================
template <int MODE, int INIT_HV>
__global__ __launch_bounds__(128, 8) void k_pass1(const float* __restrict__ edges,
                                                  const float* __restrict__ We,
                                                  const float* __restrict__ Wu,
                                                  const float* __restrict__ Wv,
                                                  const float* __restrict__ Ww,
                                                  const float* __restrict__ Wr,
                                                  const float* __restrict__ nodes,
                                                  float* __restrict__ hv_io,
                                                  const float* __restrict__ hw_in,
                                                  float* __restrict__ hw_out,
                                                  const float* __restrict__ hid_in,
                                                  float* __restrict__ hidden,
                                                  float* __restrict__ out) {
    __shared__ float4 e_s[N_];             // 2 KB
    __shared__ float  asum_part[2];
    __shared__ unsigned qmask_s[4];
    __shared__ float  hid_s[H_];
    __shared__ float  msg_s[H_];
    __shared__ float  hn_s[H_];
    __shared__ float  nod_s[H_];           // MODE 2 only
    __shared__ float  red_s[H_];           // MODE 2 only

    // batch-affine swizzle: co-resident blocks (≡ mod 256) share batch b
    const int bx = blockIdx.x;             // grid = 4096
    const int cu = bx & 255, slot = bx >> 8;    // slot 0..15
    const int b = cu >> 3;
    const int vt = (cu & 7) + slot * 8;    // 0..127
    const int row = b * N_ + vt;

    const int t = threadIdx.x, j = t;      // one row, j == t
    const int wv = t >> 6, lane = t & 63;
    const bool act = (j < H_);

    {   // stage this row's edges; ballot edge-mask bits; row sum
        const float4* eg = (const float4*)(edges + (size_t)row * N_ * 4);
        const float4 e = eg[t];            // coalesced, t == w
        e_s[t] = e;
        float s = (e.x + e.y) + (e.z + e.w);
        const unsigned long long bal = __ballot(s != 0.f);
        if (lane == 0) {
            qmask_s[wv * 2]     = (unsigned)bal;
            qmask_s[wv * 2 + 1] = (unsigned)(bal >> 32);
        }
#pragma unroll
        for (int off = 32; off > 0; off >>= 1) s += __shfl_down(s, off);
        if (lane == 0) asum_part[wv] = s;
    }
    {   // stage pre-update hidden row (25 float4); nodes too if readout pass
        const float4* hg = (const float4*)(hid_in + (size_t)row * H_);
        if (t < 25) ((float4*)hid_s)[t] = hg[t];
        if (MODE == 2) {
            const float4* ng = (const float4*)(nodes + (size_t)row * H_);
            if (t < 25) ((float4*)nod_s)[t] = ng[t];
        }
    }
    __syncthreads();

    const float nm = ((asum_part[0] + asum_part[1]) != 0.f) ? 1.f : 0.f;

    if (act) {
        float hvv;
        if (INIT_HV) {      // pass 1: hv = hid @ Wv computed in-register
            const float4* h4p = (const float4*)hid_s;
            float va = 0.f;
#pragma unroll 5
            for (int k4 = 0; k4 < 25; ++k4) {
                const float4 h4 = h4p[k4];
                const int k = k4 * 4;
                va = fmaf(h4.x, Wv[(k + 0) * H_ + j], va);
                va = fmaf(h4.y, Wv[(k + 1) * H_ + j], va);
                va = fmaf(h4.z, Wv[(k + 2) * H_ + j], va);
                va = fmaf(h4.w, Wv[(k + 3) * H_ + j], va);
            }
            hvv = va;
        } else {
            hvv = hv_io[(size_t)row * H_ + j];
        }
        const float we0 = We[0 * H_ + j], we1 = We[1 * H_ + j];
        const float we2 = We[2 * H_ + j], we3 = We[3 * H_ + j];
        const float* hwp = hw_in + (size_t)b * N_ * H_ + j;
        float acc = 0.f;
        for (int c = 0; c < 4; ++c) {             // 4 chunks of 32 w
            const unsigned mq =
                __builtin_amdgcn_readfirstlane(qmask_s[c]);  // SGPR, uniform
            const float4* ec = &e_s[c * 32];
            const float*  hc = hwp + (size_t)(c * 32) * H_;
#pragma unroll 8
            for (int w8 = 0; w8 < 32; ++w8) {
                const float4 e = ec[w8];          // LDS b128 broadcast
                const float  hww = hc[w8 * H_];   // coalesced; L1-hot w/ swizzle
                const float  m = ((mq >> w8) & 1u) ? 1.f : 0.f;  // SALU cselect
                float p = hvv + hww;
                p = fmaf(e.x, we0, p);
                p = fmaf(e.y, we1, p);
                p = fmaf(e.z, we2, p);
                p = fmaf(e.w, we3, p);
                acc = fmaf(m, fmaxf(p, 0.f), acc);
            }
        }
        msg_s[j] = acc;
    }
    __syncthreads();

    if (act) {
        const float4* h4p = (const float4*)hid_s;
        const float4* m4p = (const float4*)msg_s;
        float u = 0.f;
#pragma unroll 5
        for (int k4 = 0; k4 < 25; ++k4) {
            const float4 h4 = h4p[k4];
            const int k = k4 * 4;
            u = fmaf(h4.x, Wu[(k + 0) * H_ + j], u);
            u = fmaf(h4.y, Wu[(k + 1) * H_ + j], u);
            u = fmaf(h4.z, Wu[(k + 2) * H_ + j], u);
            u = fmaf(h4.w, Wu[(k + 3) * H_ + j], u);
        }
#pragma unroll 5
        for (int k4 = 0; k4 < 25; ++k4) {
            const float4 m4 = m4p[k4];
            const int k = H_ + k4 * 4;
            u = fmaf(m4.x, Wu[(k + 0) * H_ + j], u);
            u = fmaf(m4.y, Wu[(k + 1) * H_ + j], u);
            u = fmaf(m4.z, Wu[(k + 2) * H_ + j], u);
            u = fmaf(m4.w, Wu[(k + 3) * H_ + j], u);
        }
        const float nh = (nm != 0.f) ? tanhf(u) : hid_s[j];
        hn_s[j] = nh;
        if (MODE == 1) hidden[(size_t)row * H_ + j] = nh;
    }
    __syncthreads();

    if (MODE == 1) {        // next pass's hv/hw from fresh hidden (own row)
        if (act) {
            const float4* h4p = (const float4*)hn_s;
            float va = 0.f, wa = 0.f;
#pragma unroll 5
            for (int k4 = 0; k4 < 25; ++k4) {
                const float4 h4 = h4p[k4];
                const int k = k4 * 4;
                va = fmaf(h4.x, Wv[(k + 0) * H_ + j], va);
                wa = fmaf(h4.x, Ww[(k + 0) * H_ + j], wa);
                va = fmaf(h4.y, Wv[(k + 1) * H_ + j], va);
                wa = fmaf(h4.y, Ww[(k + 1) * H_ + j], wa);
                va = fmaf(h4.z, Wv[(k + 2) * H_ + j], va);
                wa = fmaf(h4.z, Ww[(k + 2) * H_ + j], wa);
                va = fmaf(h4.w, Wv[(k + 3) * H_ + j], va);
                wa = fmaf(h4.w, Ww[(k + 3) * H_ + j], wa);
            }
            hv_io[(size_t)row * H_ + j] = va;     // row-local: safe in-place
            hw_out[(size_t)row * H_ + j] = wa;    // double-buffered
        }
    } else {                // MODE 2: fused readout
        if (act) {
            const float4* h4p = (const float4*)hn_s;
            const float4* n4p = (const float4*)nod_s;
            float u = 0.f;
#pragma unroll 5
            for (int k4 = 0; k4 < 25; ++k4) {
                const float4 h4 = h4p[k4];
                const int k = k4 * 4;
                u = fmaf(h4.x, Wr[(k + 0) * H_ + j], u);
                u = fmaf(h4.y, Wr[(k + 1) * H_ + j], u);
                u = fmaf(h4.z, Wr[(k + 2) * H_ + j], u);
                u = fmaf(h4.w, Wr[(k + 3) * H_ + j], u);
            }
#pragma unroll 5
            for (int k4 = 0; k4 < 25; ++k4) {
                const float4 n4 = n4p[k4];
                const int k = H_ + k4 * 4;
                u = fmaf(n4.x, Wr[(k + 0) * H_ + j], u);
                u = fmaf(n4.y, Wr[(k + 1) * H_ + j], u);
                u = fmaf(n4.z, Wr[(k + 2) * H_ + j], u);
                u = fmaf(n4.w, Wr[(k + 3) * H_ + j], u);
            }
            red_s[j] = nm * fmaxf(u, 0.f);
        }
        __syncthreads();
        if (t < H_) atomicAdd(out + b * H_ + t, red_s[t]);
    }
}

// ===========================================================================
// B-variant (pass 2): the proven r0 256-thread two-row kernel, unchanged.
// ===========================================================================
template <int MODE, int INIT_HV>
__global__ __launch_bounds__(256, 6) void k_pass(const float* __restrict__ edges,
                                                 const float* __restrict__ We,
                                                 const float* __restrict__ Wu,
                                                 const float* __restrict__ Wv,
                                                 const float* __restrict__ Ww,
                                                 const float* __restrict__ Wr,
                                                 const float* __restrict__ nodes,
                                                 float* __restrict__ hv_io,
                                                 const float* __restrict__ hw_in,
                                                 float* __restrict__ hw_out,
                                                 const float* __restrict__ hid_in,
                                                 float* __restrict__ hidden,
                                                 float* __restrict__ out) {
    __shared__ float4 e_s[2][N_];
    __shared__ float  asum_part[4];
    __shared__ unsigned qmask_s[2][4];
    __shared__ float  hid_s[2][H_];
    __shared__ float  msg_s[2][H_];
    __shared__ float  hn_s[2][H_];
    __shared__ float  nod_s[2][H_];
    __shared__ float  red_s[2][H_];

    const int bx = blockIdx.x;
    const int cu = bx & 255, slot = bx >> 8;
    const int b = cu >> 3;
    const int vt = (cu & 7) + slot * 8;
    const int row0 = b * N_ + vt * 2;

    const int t = threadIdx.x, r = t >> 7, j = t & 127;
    const int wv = t >> 6, lane = t & 63;
    const int row = row0 + r;
    const bool act = (j < H_);

    {
        const float4* eg = (const float4*)(edges + (size_t)row0 * N_ * 4);
        const float4 e = eg[t];
        e_s[r][j] = e;
        float s = (e.x + e.y) + (e.z + e.w);
        const unsigned long long bal = __ballot(s != 0.f);
        if (lane == 0) {
            qmask_s[wv >> 1][(wv & 1) * 2]     = (unsigned)bal;
            qmask_s[wv >> 1][(wv & 1) * 2 + 1] = (unsigned)(bal >> 32);
        }
#pragma unroll
        for (int off = 32; off > 0; off >>= 1) s += __shfl_down(s, off);
        if (lane == 0) asum_part[wv] = s;
    }
    {
        const float4* hg = (const float4*)(hid_in + (size_t)row0 * H_);
        if (t < 50) ((float4*)hid_s)[t] = hg[t];
        if (MODE == 2) {
            const float4* ng = (const float4*)(nodes + (size_t)row0 * H_);
            if (t < 50) ((float4*)nod_s)[t] = ng[t];
        }
    }
    __syncthreads();

    const float nm = ((asum_part[2 * r] + asum_part[2 * r + 1]) != 0.f) ? 1.f : 0.f;

    if (act) {
        float hvv;
        if (INIT_HV) {
            const float4* h4p = (const float4*)hid_s[r];
            float va = 0.f;
#pragma unroll 5
            for (int k4 = 0; k4 < 25; ++k4) {
                const float4 h4 = h4p[k4];
                const int k = k4 * 4;
                va = fmaf(h4.x, Wv[(k + 0) * H_ + j], va);
                va = fmaf(h4.y, Wv[(k + 1) * H_ + j], va);
                va = fmaf(h4.z, Wv[(k + 2) * H_ + j], va);
                va = fmaf(h4.w, Wv[(k + 3) * H_ + j], va);
            }
            hvv = va;
        } else {
            hvv = hv_io[(size_t)row * H_ + j];
        }
        const float we0 = We[0 * H_ + j], we1 = We[1 * H_ + j];
        const float we2 = We[2 * H_ + j], we3 = We[3 * H_ + j];
        const float* hwp = hw_in + (size_t)b * N_ * H_ + j;
        float acc = 0.f;
        for (int c = 0; c < 4; ++c) {
            const unsigned mq =
                __builtin_amdgcn_readfirstlane(qmask_s[r][c]);
            const float4* ec = &e_s[r][c * 32];
            const float*  hc = hwp + (size_t)(c * 32) * H_;
#pragma unroll 8
            for (int w8 = 0; w8 < 32; ++w8) {
                const float4 e = ec[w8];
                const float  hww = hc[w8 * H_];
                const float  m = ((mq >> w8) & 1u) ? 1.f : 0.f;
                float p = hvv + hww;
                p = fmaf(e.x, we0, p);
                p = fmaf(e.y, we1, p);
                p = fmaf(e.z, we2, p);
                p = fmaf(e.w, we3, p);
                acc = fmaf(m, fmaxf(p, 0.f), acc);
            }
        }
        msg_s[r][j] = acc;
    }
    __syncthreads();

    if (act) {
        const float4* h4p = (const float4*)hid_s[r];
        const float4* m4p = (const float4*)msg_s[r];
        float u = 0.f;
#pragma unroll 5
        for (int k4 = 0; k4 < 25; ++k4) {
            const float4 h4 = h4p[k4];
            const int k = k4 * 4;
            u = fmaf(h4.x, Wu[(k + 0) * H_ + j], u);
            u = fmaf(h4.y, Wu[(k + 1) * H_ + j], u);
            u = fmaf(h4.z, Wu[(k + 2) * H_ + j], u);
            u = fmaf(h4.w, Wu[(k + 3) * H_ + j], u);
        }
#pragma unroll 5
        for (int k4 = 0; k4 < 25; ++k4) {
            const float4 m4 = m4p[k4];
            const int k = H_ + k4 * 4;
            u = fmaf(m4.x, Wu[(k + 0) * H_ + j], u);
            u = fmaf(m4.y, Wu[(k + 1) * H_ + j], u);
            u = fmaf(m4.z, Wu[(k + 2) * H_ + j], u);
            u = fmaf(m4.w, Wu[(k + 3) * H_ + j], u);
        }
        const float nh = (nm != 0.f) ? tanhf(u) : hid_s[r][j];
        hn_s[r][j] = nh;
        if (MODE == 1) hidden[(size_t)row * H_ + j] = nh;
    }
    __syncthreads();

    if (MODE == 1) {
        if (act) {
            const float4* h4p = (const float4*)hn_s[r];
            float va = 0.f, wa = 0.f;
#pragma unroll 5
            for (int k4 = 0; k4 < 25; ++k4) {
                const float4 h4 = h4p[k4];
                const int k = k4 * 4;
                va = fmaf(h4.x, Wv[(k + 0) * H_ + j], va);
                wa = fmaf(h4.x, Ww[(k + 0) * H_ + j], wa);
                va = fmaf(h4.y, Wv[(k + 1) * H_ + j], va);
                wa = fmaf(h4.y, Ww[(k + 1) * H_ + j], wa);
                va = fmaf(h4.z, Wv[(k + 2) * H_ + j], va);
                wa = fmaf(h4.z, Ww[(k + 2) * H_ + j], wa);
                va = fmaf(h4.w, Wv[(k + 3) * H_ + j], va);
                wa = fmaf(h4.w, Ww[(k + 3) * H_ + j], wa);
            }
            hv_io[(size_t)row * H_ + j] = va;
            hw_out[(size_t)row * H_ + j] = wa;
        }
    } else {
        if (act) {
            const float4* h4p = (const float4*)hn_s[r];
            const float4* n4p = (const float4*)nod_s[r];
            float u = 0.f;
#pragma unroll 5
            for (int k4 = 0; k4 < 25; ++k4) {
                const float4 h4 = h4p[k4];
                const int k = k4 * 4;
                u = fmaf(h4.x, Wr[(k + 0) * H_ + j], u);
                u = fmaf(h4.y, Wr[(k + 1) * H_ + j], u);
                u = fmaf(h4.z, Wr[(k + 2) * H_ + j], u);
                u = fmaf(h4.w, Wr[(k + 3) * H_ + j], u);
            }
#pragma unroll 5
            for (int k4 = 0; k4 < 25; ++k4) {
                const float4 n4 = n4p[k4];
                const int k = H_ + k4 * 4;
                u = fmaf(n4.x, Wr[(k + 0) * H_ + j], u);
                u = fmaf(n4.y, Wr[(k + 1) * H_ + j], u);
                u = fmaf(n4.z, Wr[(k + 2) * H_ + j], u);
                u = fmaf(n4.w, Wr[(k + 3) * H_ + j], u);
            }
            red_s[r][j] = nm * fmaxf(u, 0.f);
        }
        __syncthreads();
        if (t < H_) atomicAdd(out + b * H_ + t, red_s[0][t] + red_s[1][t]);
    }
}

// ---------------------------------------------------------------------------
extern "C" void kernel_launch(void* const* d_in, const int* in_sizes, int n_in,
                              void* d_out, int out_size, void* d_ws, size_t ws_size,
                              hipStream_t stream) {
    const float* nodes = (const float*)d_in[0];
    const float* edges = (const float*)d_in[1];
    const float* Wv    = (const float*)d_in[2];
    const float* Ww    = (const float*)d_in[3];
    const float* We    = (const float*)d_in[4];
    const float* Wu    = (const float*)d_in[5];
    const float* Wr    = (const float*)d_in[6];
    float* out = (float*)d_out;

    float* hidden = (float*)d_ws;     // RH
    float* hv     = hidden + RH;      // RH
    float* hwA    = hv + RH;          // RH
    float* hwB    = hwA + RH;         // RH

    k_proj0<<<ROWS / 2, 256, 0, stream>>>(nodes, Ww, hwA, out);

    // pass 1: NEW 128-thread single-row geometry (A-variant)
    k_pass1<1, 1><<<ROWS, 128, 0, stream>>>(edges, We, Wu, Wv, Ww, Wr, nodes,
                                            hv, hwA, hwB, nodes, hidden, out);
    // pass 2: proven 256-thread two-row geometry (B-variant, control)
    k_pass<1, 0><<<ROWS / 2, 256, 0, stream>>>(edges, We, Wu, Wv, Ww, Wr, nodes,
                                               hv, hwB, hwA, hidden, hidden, out);
    // pass 3: NEW 128-thread single-row geometry (A-variant, readout)
    k_pass1<2, 0><<<ROWS, 128, 0, stream>>>(edges, We, Wu, Wv, Ww, Wr, nodes,
                                            hv, hwA, hwB, hidden, hidden, out);
}